// Round 1
// baseline (4751.259 us; speedup 1.0000x reference)
//
#include <hip/hip_runtime.h>
#include <math.h>

#define NB 8
#define SL 2048
#define WD 1024
#define NH 8
#define DH 128
#define HD 1024
#define MROWS (NB * SL)

// ---------------- Q/K/V projection: C = X(16384x1024) @ W(1024x1024)^T -------
// W rows are (h*128+d), cols w. Output scattered to [N,H,S,D]. 1/sqrt(D) folded
// into Q at store. grid (16, 256, 3), block 256.
__global__ __launch_bounds__(256) void proj_kernel(
    const float* __restrict__ x,
    const float* __restrict__ WQ, const float* __restrict__ WK,
    const float* __restrict__ WV,
    float* __restrict__ qo, float* __restrict__ ko, float* __restrict__ vo)
{
    const int which = blockIdx.z;
    const float* __restrict__ B = (which == 0) ? WQ : (which == 1) ? WK : WV;
    float* __restrict__ C = (which == 0) ? qo : (which == 1) ? ko : vo;
    const float scale = (which == 0) ? 0.08838834764831845f : 1.0f;

    const int m0 = blockIdx.y * 64;
    const int j0 = blockIdx.x * 64;
    const int tid = threadIdx.x;
    const int tx = tid & 15;
    const int ty = tid >> 4;

    __shared__ float As[16][64];
    __shared__ float Bs[16][64];

    float acc[4][4];
#pragma unroll
    for (int i = 0; i < 4; ++i)
#pragma unroll
        for (int j = 0; j < 4; ++j) acc[i][j] = 0.0f;

    const int lrow = tid >> 2;   // 0..63
    const int lkq  = tid & 3;    // 0..3
    const float* Aptr = x + (size_t)(m0 + lrow) * WD + lkq * 4;
    const float* Bptr = B + (size_t)(j0 + lrow) * WD + lkq * 4;

    float4 av = *(const float4*)Aptr;
    float4 bv = *(const float4*)Bptr;

    for (int k0 = 0; k0 < WD; k0 += 16) {
        __syncthreads();
        As[lkq * 4 + 0][lrow] = av.x;
        As[lkq * 4 + 1][lrow] = av.y;
        As[lkq * 4 + 2][lrow] = av.z;
        As[lkq * 4 + 3][lrow] = av.w;
        Bs[lkq * 4 + 0][lrow] = bv.x;
        Bs[lkq * 4 + 1][lrow] = bv.y;
        Bs[lkq * 4 + 2][lrow] = bv.z;
        Bs[lkq * 4 + 3][lrow] = bv.w;
        __syncthreads();
        if (k0 + 16 < WD) {  // prefetch next tile; overlaps with compute below
            av = *(const float4*)(Aptr + k0 + 16);
            bv = *(const float4*)(Bptr + k0 + 16);
        }
#pragma unroll
        for (int kk = 0; kk < 16; ++kk) {
            const float4 a = *(const float4*)&As[kk][ty * 4];
            const float4 b = *(const float4*)&Bs[kk][tx * 4];
            const float ar[4] = {a.x, a.y, a.z, a.w};
            const float br[4] = {b.x, b.y, b.z, b.w};
#pragma unroll
            for (int i = 0; i < 4; ++i)
#pragma unroll
                for (int j = 0; j < 4; ++j) acc[i][j] += ar[i] * br[j];
        }
    }

    const int n = m0 / SL;
    const int sbase = m0 % SL;
    const int h = j0 >> 7;                 // tile never straddles a head (64|128)
    const int dbase = (j0 & 127) + tx * 4;
    float* Cb = C + (size_t)(n * NH + h) * SL * DH;
#pragma unroll
    for (int rr = 0; rr < 4; ++rr) {
        const int s = sbase + ty * 4 + rr;
        float4 o;
        o.x = acc[rr][0] * scale;
        o.y = acc[rr][1] * scale;
        o.z = acc[rr][2] * scale;
        o.w = acc[rr][3] * scale;
        *(float4*)(Cb + (size_t)s * DH + dbase) = o;
    }
}

// ---------------- Flash attention, fp32. BQ=64, BT=32, 256 threads. ----------
// q prescaled by 1/sqrt(D). q,k,v in [N,H,S,D]. z written as [N,S,H*D].
// Q,K staged in LDS (stride 132 kills bank conflicts); V read from global
// (uniform row per step -> one 256B segment per instr, L1-resident tile).
__global__ __launch_bounds__(256) void attn_kernel(
    const float* __restrict__ q, const float* __restrict__ k,
    const float* __restrict__ v, float* __restrict__ z)
{
    const int nh = blockIdx.y;
    const int n = nh >> 3;
    const int h = nh & 7;
    const int q0 = blockIdx.x * 64;
    const size_t base = (size_t)nh * SL * DH;

    const int tid = threadIdx.x;
    const int tx = tid & 15;   // column group (scores) / d group (PV)
    const int ty = tid >> 4;   // row group: rows ty*4 .. ty*4+3

    __shared__ float Qs[64][132];
    __shared__ float Ks[32][132];
    __shared__ float Ps[64][33];

    // stage Q once
    {
        const int row = tid >> 2;
        const int c4 = tid & 3;
        const float* src = q + base + (size_t)(q0 + row) * DH;
#pragma unroll
        for (int i = 0; i < 8; ++i) {
            const int g = c4 + i * 4;
            *(float4*)&Qs[row][g * 4] = *(const float4*)(src + g * 4);
        }
    }

    float accv[4][8];
    float mrun[4], lrun[4];
#pragma unroll
    for (int rr = 0; rr < 4; ++rr) {
        mrun[rr] = -INFINITY;
        lrun[rr] = 0.0f;
#pragma unroll
        for (int d = 0; d < 8; ++d) accv[rr][d] = 0.0f;
    }

    const int row8 = tid >> 3;   // 0..31
    const int q8 = tid & 7;      // 0..7
    const float* kp = k + base + (size_t)row8 * DH + q8 * 4;
    const float* vb = v + base;

    float4 kreg[4];
#pragma unroll
    for (int i = 0; i < 4; ++i) kreg[i] = *(const float4*)(kp + i * 32);

    for (int t = 0; t < 64; ++t) {
        __syncthreads();   // prior tile's K reads done
#pragma unroll
        for (int i = 0; i < 4; ++i)
            *(float4*)&Ks[row8][(q8 + 8 * i) * 4] = kreg[i];
        __syncthreads();
        if (t + 1 < 64) {  // prefetch next K tile into regs (overlaps compute)
            const size_t off = (size_t)(t + 1) * 32 * DH;
#pragma unroll
            for (int i = 0; i < 4; ++i)
                kreg[i] = *(const float4*)(kp + off + i * 32);
        }

        // ---- scores: 4 rows x 2 cols (cols tx and tx+16) ----
        float sc[4][2];
#pragma unroll
        for (int rr = 0; rr < 4; ++rr) { sc[rr][0] = 0.0f; sc[rr][1] = 0.0f; }
#pragma unroll 8
        for (int g = 0; g < 32; ++g) {
            const float4 b0 = *(const float4*)&Ks[tx][g * 4];
            const float4 b1 = *(const float4*)&Ks[tx + 16][g * 4];
#pragma unroll
            for (int rr = 0; rr < 4; ++rr) {
                const float4 a = *(const float4*)&Qs[ty * 4 + rr][g * 4];
                sc[rr][0] += a.x * b0.x; sc[rr][0] += a.y * b0.y;
                sc[rr][0] += a.z * b0.z; sc[rr][0] += a.w * b0.w;
                sc[rr][1] += a.x * b1.x; sc[rr][1] += a.y * b1.y;
                sc[rr][1] += a.z * b1.z; sc[rr][1] += a.w * b1.w;
            }
        }

        // ---- online softmax (per-row state replicated across the 16 tx lanes)
#pragma unroll
        for (int rr = 0; rr < 4; ++rr) {
            float tmax = fmaxf(sc[rr][0], sc[rr][1]);
#pragma unroll
            for (int o = 1; o < 16; o <<= 1)
                tmax = fmaxf(tmax, __shfl_xor(tmax, o, 64));
            const float mn = fmaxf(mrun[rr], tmax);
            const float ef = __expf(mrun[rr] - mn);  // 0 on first tile (-inf)
            mrun[rr] = mn;
            const float p0 = __expf(sc[rr][0] - mn);
            const float p1 = __expf(sc[rr][1] - mn);
            float ps = p0 + p1;
#pragma unroll
            for (int o = 1; o < 16; o <<= 1) ps += __shfl_xor(ps, o, 64);
            lrun[rr] = lrun[rr] * ef + ps;
#pragma unroll
            for (int d = 0; d < 8; ++d) accv[rr][d] *= ef;
            Ps[ty * 4 + rr][tx] = p0;        // col index == K/V row index
            Ps[ty * 4 + rr][tx + 16] = p1;
        }
        // P rows of this wave are written and read by the same wave only:
        // in-order DS pipe => no barrier needed before PV.

        // ---- PV: acc[4 rows][8 d], d = tx*4+c (+64) ----
        const float* vt = vb + (size_t)t * 32 * DH;
#pragma unroll 4
        for (int tt = 0; tt < 32; ++tt) {
            const float4 v0 = *(const float4*)(vt + (size_t)tt * DH + tx * 4);
            const float4 v1 = *(const float4*)(vt + (size_t)tt * DH + tx * 4 + 64);
#pragma unroll
            for (int rr = 0; rr < 4; ++rr) {
                const float p = Ps[ty * 4 + rr][tt];
                accv[rr][0] += p * v0.x; accv[rr][1] += p * v0.y;
                accv[rr][2] += p * v0.z; accv[rr][3] += p * v0.w;
                accv[rr][4] += p * v1.x; accv[rr][5] += p * v1.y;
                accv[rr][6] += p * v1.z; accv[rr][7] += p * v1.w;
            }
        }
    }

    float* zb = z + ((size_t)n * SL + q0) * HD + h * DH;
#pragma unroll
    for (int rr = 0; rr < 4; ++rr) {
        const float inv = 1.0f / lrun[rr];
        float4 o0, o1;
        o0.x = accv[rr][0] * inv; o0.y = accv[rr][1] * inv;
        o0.z = accv[rr][2] * inv; o0.w = accv[rr][3] * inv;
        o1.x = accv[rr][4] * inv; o1.y = accv[rr][5] * inv;
        o1.z = accv[rr][6] * inv; o1.w = accv[rr][7] * inv;
        *(float4*)(zb + (size_t)(ty * 4 + rr) * HD + tx * 4) = o0;
        *(float4*)(zb + (size_t)(ty * 4 + rr) * HD + tx * 4 + 64) = o1;
    }
}

// ---------------- Output projection: out = Z(16384x1024) @ WZ(128x1024)^T ----
__global__ __launch_bounds__(256) void outproj_kernel(
    const float* __restrict__ z, const float* __restrict__ WZ,
    float* __restrict__ out)
{
    const int m0 = blockIdx.x * 64;
    const int tid = threadIdx.x;
    const int tx = tid & 15;
    const int ty = tid >> 4;

    __shared__ float As[16][64];
    __shared__ float Bs[16][128];

    float acc[4][8];
#pragma unroll
    for (int i = 0; i < 4; ++i)
#pragma unroll
        for (int j = 0; j < 8; ++j) acc[i][j] = 0.0f;

    const int arow = tid >> 2, akq = tid & 3;
    const float* Ap = z + (size_t)(m0 + arow) * HD + akq * 4;
    const int bcol = tid >> 1, bkh = tid & 1;
    const float* Bp = WZ + (size_t)bcol * HD + bkh * 8;

    float4 av = *(const float4*)Ap;
    float4 bv0 = *(const float4*)Bp;
    float4 bv1 = *(const float4*)(Bp + 4);

    for (int k0 = 0; k0 < HD; k0 += 16) {
        __syncthreads();
        As[akq * 4 + 0][arow] = av.x;
        As[akq * 4 + 1][arow] = av.y;
        As[akq * 4 + 2][arow] = av.z;
        As[akq * 4 + 3][arow] = av.w;
        Bs[bkh * 8 + 0][bcol] = bv0.x;
        Bs[bkh * 8 + 1][bcol] = bv0.y;
        Bs[bkh * 8 + 2][bcol] = bv0.z;
        Bs[bkh * 8 + 3][bcol] = bv0.w;
        Bs[bkh * 8 + 4][bcol] = bv1.x;
        Bs[bkh * 8 + 5][bcol] = bv1.y;
        Bs[bkh * 8 + 6][bcol] = bv1.z;
        Bs[bkh * 8 + 7][bcol] = bv1.w;
        __syncthreads();
        if (k0 + 16 < HD) {
            av = *(const float4*)(Ap + k0 + 16);
            bv0 = *(const float4*)(Bp + k0 + 16);
            bv1 = *(const float4*)(Bp + k0 + 20);
        }
#pragma unroll
        for (int kk = 0; kk < 16; ++kk) {
            const float4 a = *(const float4*)&As[kk][ty * 4];
            const float4 b0 = *(const float4*)&Bs[kk][tx * 4];
            const float4 b1 = *(const float4*)&Bs[kk][tx * 4 + 64];
            const float ar[4] = {a.x, a.y, a.z, a.w};
            const float br[8] = {b0.x, b0.y, b0.z, b0.w, b1.x, b1.y, b1.z, b1.w};
#pragma unroll
            for (int i = 0; i < 4; ++i)
#pragma unroll
                for (int j = 0; j < 8; ++j) acc[i][j] += ar[i] * br[j];
        }
    }

    float* ob = out + (size_t)m0 * DH;
#pragma unroll
    for (int rr = 0; rr < 4; ++rr) {
        float4 o0, o1;
        o0.x = acc[rr][0]; o0.y = acc[rr][1]; o0.z = acc[rr][2]; o0.w = acc[rr][3];
        o1.x = acc[rr][4]; o1.y = acc[rr][5]; o1.z = acc[rr][6]; o1.w = acc[rr][7];
        *(float4*)(ob + (size_t)(ty * 4 + rr) * DH + tx * 4) = o0;
        *(float4*)(ob + (size_t)(ty * 4 + rr) * DH + tx * 4 + 64) = o1;
    }
}

extern "C" void kernel_launch(void* const* d_in, const int* in_sizes, int n_in,
                              void* d_out, int out_size, void* d_ws, size_t ws_size,
                              hipStream_t stream)
{
    const float* x  = (const float*)d_in[0];
    const float* WQ = (const float*)d_in[1];
    const float* WK = (const float*)d_in[2];
    const float* WV = (const float*)d_in[3];
    const float* WZ = (const float*)d_in[4];
    float* out = (float*)d_out;

    float* ws = (float*)d_ws;
    const size_t SZ = (size_t)MROWS * HD;   // 16,777,216 floats = 64 MiB
    float* q = ws;
    float* k = ws + SZ;
    float* v = ws + 2 * SZ;
    float* z = ws + 3 * SZ;                 // total 256 MiB of workspace

    dim3 gp(16, 256, 3);
    hipLaunchKernelGGL(proj_kernel, gp, dim3(256), 0, stream,
                       x, WQ, WK, WV, q, k, v);

    dim3 ga(SL / 64, NB * NH);
    hipLaunchKernelGGL(attn_kernel, ga, dim3(256), 0, stream, q, k, v, z);

    hipLaunchKernelGGL(outproj_kernel, dim3(MROWS / 64), dim3(256), 0, stream,
                       z, WZ, out);
}

// Round 2
// 2097.080 us; speedup vs baseline: 2.2657x; 2.2657x over previous
//
#include <hip/hip_runtime.h>
#include <math.h>

#define NB 8
#define SL 2048
#define WD 1024
#define NH 8
#define DH 128
#define HD 1024
#define MROWS (NB * SL)

typedef __bf16 bf16x8 __attribute__((ext_vector_type(8)));
typedef float f32x16 __attribute__((ext_vector_type(16)));

__device__ inline unsigned f2bf_bits(float x) {          // RNE bf16, return bits
    unsigned u = __float_as_uint(x);
    unsigned r = u + 0x7FFFu + ((u >> 16) & 1u);
    return r >> 16;
}
__device__ inline float bf2f(unsigned bits) { return __uint_as_float(bits << 16); }
__device__ inline unsigned pack2bf(float a, float b) {
    return f2bf_bits(a) | (f2bf_bits(b) << 16);
}

// ---------------- Q/K/V projection: C = X(16384x1024) @ W(1024x1024)^T -------
// Q gets scale log2(e)/sqrt(128) folded in (attention uses exp2).
__global__ __launch_bounds__(256) void proj_kernel(
    const float* __restrict__ x,
    const float* __restrict__ WQ, const float* __restrict__ WK,
    const float* __restrict__ WV,
    float* __restrict__ qo, float* __restrict__ ko, float* __restrict__ vo)
{
    const int which = blockIdx.z;
    const float* __restrict__ B = (which == 0) ? WQ : (which == 1) ? WK : WV;
    float* __restrict__ C = (which == 0) ? qo : (which == 1) ? ko : vo;
    const float scale = (which == 0) ? 0.12751743f : 1.0f;  // log2e/sqrt(128)

    const int m0 = blockIdx.y * 64;
    const int j0 = blockIdx.x * 64;
    const int tid = threadIdx.x;
    const int tx = tid & 15;
    const int ty = tid >> 4;

    __shared__ float As[16][64];
    __shared__ float Bs[16][64];

    float acc[4][4];
#pragma unroll
    for (int i = 0; i < 4; ++i)
#pragma unroll
        for (int j = 0; j < 4; ++j) acc[i][j] = 0.0f;

    const int lrow = tid >> 2;
    const int lkq  = tid & 3;
    const float* Aptr = x + (size_t)(m0 + lrow) * WD + lkq * 4;
    const float* Bptr = B + (size_t)(j0 + lrow) * WD + lkq * 4;

    float4 av = *(const float4*)Aptr;
    float4 bv = *(const float4*)Bptr;

    for (int k0 = 0; k0 < WD; k0 += 16) {
        __syncthreads();
        As[lkq * 4 + 0][lrow] = av.x;
        As[lkq * 4 + 1][lrow] = av.y;
        As[lkq * 4 + 2][lrow] = av.z;
        As[lkq * 4 + 3][lrow] = av.w;
        Bs[lkq * 4 + 0][lrow] = bv.x;
        Bs[lkq * 4 + 1][lrow] = bv.y;
        Bs[lkq * 4 + 2][lrow] = bv.z;
        Bs[lkq * 4 + 3][lrow] = bv.w;
        __syncthreads();
        if (k0 + 16 < WD) {
            av = *(const float4*)(Aptr + k0 + 16);
            bv = *(const float4*)(Bptr + k0 + 16);
        }
#pragma unroll
        for (int kk = 0; kk < 16; ++kk) {
            const float4 a = *(const float4*)&As[kk][ty * 4];
            const float4 b = *(const float4*)&Bs[kk][tx * 4];
            const float ar[4] = {a.x, a.y, a.z, a.w};
            const float br[4] = {b.x, b.y, b.z, b.w};
#pragma unroll
            for (int i = 0; i < 4; ++i)
#pragma unroll
                for (int j = 0; j < 4; ++j) acc[i][j] += ar[i] * br[j];
        }
    }

    const int n = m0 / SL;
    const int sbase = m0 % SL;
    const int h = j0 >> 7;
    const int dbase = (j0 & 127) + tx * 4;
    float* Cb = C + (size_t)(n * NH + h) * SL * DH;
#pragma unroll
    for (int rr = 0; rr < 4; ++rr) {
        const int s = sbase + ty * 4 + rr;
        float4 o;
        o.x = acc[rr][0] * scale;
        o.y = acc[rr][1] * scale;
        o.z = acc[rr][2] * scale;
        o.w = acc[rr][3] * scale;
        *(float4*)(Cb + (size_t)s * DH + dbase) = o;
    }
}

// ---------------- Flash attention, MFMA 32x32x16 bf16, hi/lo split QK^T ------
// Swapped QK^T: S^T = mfma(K, Q) so each lane owns one q column (col = lane&31).
// Q hi/lo in registers; K hi/lo + V^T staged in LDS per 64-key tile.
// PV: O^T = mfma(V^T, P^T); P^T built in-register (packed bf16 + half swap).
__global__ __launch_bounds__(256, 1) void attn_kernel(
    const float* __restrict__ q, const float* __restrict__ k,
    const float* __restrict__ v, float* __restrict__ z)
{
    __shared__ __align__(16) char smem[53248];
    ushort (*Kh)[136] = (ushort (*)[136])smem;              // 64 x 136 bf16
    ushort (*Kl)[136] = (ushort (*)[136])(smem + 17408);    // 64 x 136 bf16
    ushort (*Vt)[72]  = (ushort (*)[72]) (smem + 34816);    // 128 x 72 bf16 (V^T)

    const int nh = blockIdx.y;
    const int n = nh >> 3, h = nh & 7;
    const size_t base = (size_t)nh * SL * DH;
    const int q0 = blockIdx.x * 128;

    const int tid = threadIdx.x;
    const int w = tid >> 6;
    const int lane = tid & 63;
    const int lq = lane & 31;     // mfma row/col index
    const int hl = lane >> 5;     // wave half

    // ---- Q rows -> registers as bf16 hi/lo B-fragments (8 chunks of k=16) ----
    bf16x8 qh[8], ql[8];
    {
        const float* qsrc = q + base + (size_t)(q0 + w * 32 + lq) * DH;
#pragma unroll
        for (int c = 0; c < 8; ++c) {
            const float* p = qsrc + c * 16 + hl * 8;
            float4 a = *(const float4*)p;
            float4 b = *(const float4*)(p + 4);
            float xs[8] = {a.x, a.y, a.z, a.w, b.x, b.y, b.z, b.w};
            union { unsigned u[4]; bf16x8 v; } H, L;
#pragma unroll
            for (int j = 0; j < 4; ++j) {
                unsigned h0 = f2bf_bits(xs[2 * j]);
                unsigned h1 = f2bf_bits(xs[2 * j + 1]);
                float l0 = xs[2 * j]     - bf2f(h0);
                float l1 = xs[2 * j + 1] - bf2f(h1);
                H.u[j] = h0 | (h1 << 16);
                L.u[j] = pack2bf(l0, l1);
            }
            qh[c] = H.v; ql[c] = L.v;
        }
    }

    f32x16 o0, o1, o2, o3;
#pragma unroll
    for (int i = 0; i < 16; ++i) { o0[i] = 0.f; o1[i] = 0.f; o2[i] = 0.f; o3[i] = 0.f; }
    float mrun = -INFINITY, lrun = 0.0f;

    const int ktRow = tid >> 5;          // 0..7
    const int kd0 = (tid & 31) * 4;      // 0..124
    const int vu = tid >> 4;             // 0..15 (t-quad)
    const int vdq = tid & 15;            // d-quad within half

    const float* kb = k + base;
    const float* vb = v + base;

#pragma unroll 1
    for (int tt = 0; tt < SL / 64; ++tt) {
        // ---- global loads for this tile (issued together) ----
        float4 kv[8];
        const float* ks = kb + (size_t)(tt * 64) * DH + kd0;
#pragma unroll
        for (int i = 0; i < 8; ++i)
            kv[i] = *(const float4*)(ks + (size_t)(i * 8 + ktRow) * DH);
        float4 vv[2][4];
        const float* vs = vb + (size_t)(tt * 64 + 4 * vu) * DH;
#pragma unroll
        for (int rep = 0; rep < 2; ++rep)
#pragma unroll
            for (int kk = 0; kk < 4; ++kk)
                vv[rep][kk] = *(const float4*)(vs + (size_t)kk * DH + vdq * 4 + rep * 64);

        __syncthreads();   // prior tile fully consumed

        // ---- K tile -> LDS as bf16 hi/lo ----
#pragma unroll
        for (int i = 0; i < 8; ++i) {
            const int t = i * 8 + ktRow;
            unsigned h0 = f2bf_bits(kv[i].x), h1 = f2bf_bits(kv[i].y);
            unsigned h2 = f2bf_bits(kv[i].z), h3 = f2bf_bits(kv[i].w);
            float l0 = kv[i].x - bf2f(h0), l1 = kv[i].y - bf2f(h1);
            float l2 = kv[i].z - bf2f(h2), l3 = kv[i].w - bf2f(h3);
            *(uint2*)&Kh[t][kd0] = make_uint2(h0 | (h1 << 16), h2 | (h3 << 16));
            *(uint2*)&Kl[t][kd0] = make_uint2(pack2bf(l0, l1), pack2bf(l2, l3));
        }
        // ---- V tile -> LDS transposed (bf16) ----
#pragma unroll
        for (int rep = 0; rep < 2; ++rep) {
            const int d0 = vdq * 4 + rep * 64;
            float4 r0 = vv[rep][0], r1 = vv[rep][1], r2 = vv[rep][2], r3 = vv[rep][3];
            *(uint2*)&Vt[d0 + 0][4 * vu] = make_uint2(pack2bf(r0.x, r1.x), pack2bf(r2.x, r3.x));
            *(uint2*)&Vt[d0 + 1][4 * vu] = make_uint2(pack2bf(r0.y, r1.y), pack2bf(r2.y, r3.y));
            *(uint2*)&Vt[d0 + 2][4 * vu] = make_uint2(pack2bf(r0.z, r1.z), pack2bf(r2.z, r3.z));
            *(uint2*)&Vt[d0 + 3][4 * vu] = make_uint2(pack2bf(r0.w, r1.w), pack2bf(r2.w, r3.w));
        }
        __syncthreads();   // tile staged

        // ---- QK^T (S^T), 3-pass hi/lo split ----
        f32x16 s0, s1;
#pragma unroll
        for (int i = 0; i < 16; ++i) { s0[i] = 0.f; s1[i] = 0.f; }
#pragma unroll
        for (int c = 0; c < 8; ++c) {
            const int col = c * 16 + hl * 8;
            bf16x8 ka0 = *(const bf16x8*)&Kh[lq][col];
            bf16x8 kb0 = *(const bf16x8*)&Kl[lq][col];
            s0 = __builtin_amdgcn_mfma_f32_32x32x16_bf16(ka0, qh[c], s0, 0, 0, 0);
            s0 = __builtin_amdgcn_mfma_f32_32x32x16_bf16(ka0, ql[c], s0, 0, 0, 0);
            s0 = __builtin_amdgcn_mfma_f32_32x32x16_bf16(kb0, qh[c], s0, 0, 0, 0);
            bf16x8 ka1 = *(const bf16x8*)&Kh[32 + lq][col];
            bf16x8 kb1 = *(const bf16x8*)&Kl[32 + lq][col];
            s1 = __builtin_amdgcn_mfma_f32_32x32x16_bf16(ka1, qh[c], s1, 0, 0, 0);
            s1 = __builtin_amdgcn_mfma_f32_32x32x16_bf16(ka1, ql[c], s1, 0, 0, 0);
            s1 = __builtin_amdgcn_mfma_f32_32x32x16_bf16(kb1, qh[c], s1, 0, 0, 0);
        }

        // ---- online softmax (lane owns q column; scores in log2 domain) ----
        float pmax = s0[0];
#pragma unroll
        for (int i = 1; i < 16; ++i) pmax = fmaxf(pmax, s0[i]);
#pragma unroll
        for (int i = 0; i < 16; ++i) pmax = fmaxf(pmax, s1[i]);
        pmax = fmaxf(pmax, __shfl_xor(pmax, 32, 64));
        const float mnew = fmaxf(mrun, pmax);
        const float ef = __builtin_amdgcn_exp2f(mrun - mnew);
        mrun = mnew;

        float psum = 0.f;
        unsigned own0[8], own1[8], swp0[8], swp1[8];
#pragma unroll
        for (int mI = 0; mI < 8; ++mI) {
            float a0 = __builtin_amdgcn_exp2f(s0[2 * mI]     - mnew);
            float a1 = __builtin_amdgcn_exp2f(s0[2 * mI + 1] - mnew);
            float b0 = __builtin_amdgcn_exp2f(s1[2 * mI]     - mnew);
            float b1 = __builtin_amdgcn_exp2f(s1[2 * mI + 1] - mnew);
            psum += (a0 + a1) + (b0 + b1);
            own0[mI] = pack2bf(a0, a1);
            own1[mI] = pack2bf(b0, b1);
        }
#pragma unroll
        for (int mI = 0; mI < 8; ++mI) {
            swp0[mI] = (unsigned)__shfl_xor((int)own0[mI], 32, 64);
            swp1[mI] = (unsigned)__shfl_xor((int)own1[mI], 32, 64);
        }
        psum += __shfl_xor(psum, 32, 64);
        lrun = lrun * ef + psum;
#pragma unroll
        for (int i = 0; i < 16; ++i) { o0[i] *= ef; o1[i] *= ef; o2[i] *= ef; o3[i] *= ef; }

        // ---- PV: O^T += V^T · P^T ----
#define PV_CHUNK(OWN, SWP, C)                                                      \
        {                                                                          \
            union { unsigned u[4]; bf16x8 v; } pf;                                 \
            const int tc = (C) & 1;                                                \
            pf.u[0] = hl ? SWP[4 * tc + 2] : OWN[4 * tc + 0];                      \
            pf.u[1] = hl ? SWP[4 * tc + 3] : OWN[4 * tc + 1];                      \
            pf.u[2] = hl ? OWN[4 * tc + 2] : SWP[4 * tc + 0];                      \
            pf.u[3] = hl ? OWN[4 * tc + 3] : SWP[4 * tc + 1];                      \
            const int tcol = (C) * 16 + hl * 8;                                    \
            bf16x8 vf0 = *(const bf16x8*)&Vt[ 0 + lq][tcol];                       \
            bf16x8 vf1 = *(const bf16x8*)&Vt[32 + lq][tcol];                       \
            bf16x8 vf2 = *(const bf16x8*)&Vt[64 + lq][tcol];                       \
            bf16x8 vf3 = *(const bf16x8*)&Vt[96 + lq][tcol];                       \
            o0 = __builtin_amdgcn_mfma_f32_32x32x16_bf16(vf0, pf.v, o0, 0, 0, 0);  \
            o1 = __builtin_amdgcn_mfma_f32_32x32x16_bf16(vf1, pf.v, o1, 0, 0, 0);  \
            o2 = __builtin_amdgcn_mfma_f32_32x32x16_bf16(vf2, pf.v, o2, 0, 0, 0);  \
            o3 = __builtin_amdgcn_mfma_f32_32x32x16_bf16(vf3, pf.v, o3, 0, 0, 0);  \
        }
        PV_CHUNK(own0, swp0, 0)
        PV_CHUNK(own0, swp0, 1)
        PV_CHUNK(own1, swp1, 2)
        PV_CHUNK(own1, swp1, 3)
#undef PV_CHUNK
    }

    // ---- epilogue: normalize, transpose via LDS, coalesced store ----
    __syncthreads();   // all waves done with K/V LDS
    const float inv = 1.0f / lrun;
    float* ot = (float*)smem + w * 1152;                 // 32 rows x stride 36
    float* zrow = z + ((size_t)n * SL + q0 + w * 32) * HD + h * DH;

    auto epi = [&](const f32x16& oc, int dsub) {
#pragma unroll
        for (int r = 0; r < 16; ++r) {
            const int dloc = (r & 3) + 8 * (r >> 2) + 4 * hl;
            ot[lq * 36 + dloc] = oc[r] * inv;
        }
        // same-wave LDS write->read: DS pipe is in-order per wave
        const int qr = lane >> 1;
        const int cb = (lane & 1) * 16;
#pragma unroll
        for (int i = 0; i < 4; ++i) {
            float4 val = *(float4*)&ot[qr * 36 + cb + 4 * i];
            *(float4*)(zrow + (size_t)qr * HD + dsub * 32 + cb + 4 * i) = val;
        }
    };
    epi(o0, 0); epi(o1, 1); epi(o2, 2); epi(o3, 3);
}

// ---------------- Output projection: out = Z(16384x1024) @ WZ(128x1024)^T ----
__global__ __launch_bounds__(256) void outproj_kernel(
    const float* __restrict__ z, const float* __restrict__ WZ,
    float* __restrict__ out)
{
    const int m0 = blockIdx.x * 64;
    const int tid = threadIdx.x;
    const int tx = tid & 15;
    const int ty = tid >> 4;

    __shared__ float As[16][64];
    __shared__ float Bs[16][128];

    float acc[4][8];
#pragma unroll
    for (int i = 0; i < 4; ++i)
#pragma unroll
        for (int j = 0; j < 8; ++j) acc[i][j] = 0.0f;

    const int arow = tid >> 2, akq = tid & 3;
    const float* Ap = z + (size_t)(m0 + arow) * HD + akq * 4;
    const int bcol = tid >> 1, bkh = tid & 1;
    const float* Bp = WZ + (size_t)bcol * HD + bkh * 8;

    float4 av = *(const float4*)Ap;
    float4 bv0 = *(const float4*)Bp;
    float4 bv1 = *(const float4*)(Bp + 4);

    for (int k0 = 0; k0 < HD; k0 += 16) {
        __syncthreads();
        As[akq * 4 + 0][arow] = av.x;
        As[akq * 4 + 1][arow] = av.y;
        As[akq * 4 + 2][arow] = av.z;
        As[akq * 4 + 3][arow] = av.w;
        Bs[bkh * 8 + 0][bcol] = bv0.x;
        Bs[bkh * 8 + 1][bcol] = bv0.y;
        Bs[bkh * 8 + 2][bcol] = bv0.z;
        Bs[bkh * 8 + 3][bcol] = bv0.w;
        Bs[bkh * 8 + 4][bcol] = bv1.x;
        Bs[bkh * 8 + 5][bcol] = bv1.y;
        Bs[bkh * 8 + 6][bcol] = bv1.z;
        Bs[bkh * 8 + 7][bcol] = bv1.w;
        __syncthreads();
        if (k0 + 16 < HD) {
            av = *(const float4*)(Ap + k0 + 16);
            bv0 = *(const float4*)(Bp + k0 + 16);
            bv1 = *(const float4*)(Bp + k0 + 20);
        }
#pragma unroll
        for (int kk = 0; kk < 16; ++kk) {
            const float4 a = *(const float4*)&As[kk][ty * 4];
            const float4 b0 = *(const float4*)&Bs[kk][tx * 4];
            const float4 b1 = *(const float4*)&Bs[kk][tx * 4 + 64];
            const float ar[4] = {a.x, a.y, a.z, a.w};
            const float br[8] = {b0.x, b0.y, b0.z, b0.w, b1.x, b1.y, b1.z, b1.w};
#pragma unroll
            for (int i = 0; i < 4; ++i)
#pragma unroll
                for (int j = 0; j < 8; ++j) acc[i][j] += ar[i] * br[j];
        }
    }

    float* ob = out + (size_t)m0 * DH;
#pragma unroll
    for (int rr = 0; rr < 4; ++rr) {
        float4 o0, o1;
        o0.x = acc[rr][0]; o0.y = acc[rr][1]; o0.z = acc[rr][2]; o0.w = acc[rr][3];
        o1.x = acc[rr][4]; o1.y = acc[rr][5]; o1.z = acc[rr][6]; o1.w = acc[rr][7];
        *(float4*)(ob + (size_t)(ty * 4 + rr) * DH + tx * 4) = o0;
        *(float4*)(ob + (size_t)(ty * 4 + rr) * DH + tx * 4 + 64) = o1;
    }
}

extern "C" void kernel_launch(void* const* d_in, const int* in_sizes, int n_in,
                              void* d_out, int out_size, void* d_ws, size_t ws_size,
                              hipStream_t stream)
{
    const float* x  = (const float*)d_in[0];
    const float* WQ = (const float*)d_in[1];
    const float* WK = (const float*)d_in[2];
    const float* WV = (const float*)d_in[3];
    const float* WZ = (const float*)d_in[4];
    float* out = (float*)d_out;

    float* ws = (float*)d_ws;
    const size_t SZ = (size_t)MROWS * HD;   // 64 MiB each
    float* q = ws;
    float* k = ws + SZ;
    float* v = ws + 2 * SZ;
    float* z = ws + 3 * SZ;

    dim3 gp(16, 256, 3);
    hipLaunchKernelGGL(proj_kernel, gp, dim3(256), 0, stream,
                       x, WQ, WK, WV, q, k, v);

    dim3 ga(SL / 128, NB * NH);
    hipLaunchKernelGGL(attn_kernel, ga, dim3(256), 0, stream, q, k, v, z);

    hipLaunchKernelGGL(outproj_kernel, dim3(MROWS / 64), dim3(256), 0, stream,
                       z, WZ, out);
}